// Round 2
// baseline (27.613 us; speedup 1.0000x reference)
//
#include <hip/hip_runtime.h>

#define KH 512
#define KW 512

__global__ __launch_bounds__(256)
void TrainableFilter_75118978007282_kernel(const float* __restrict__ x,
                                           const float* __restrict__ wsp,
                                           float* __restrict__ out) {
    // grid: (W/64, H/4, B*C), block (64,4)
    const int w = blockIdx.x * 64 + threadIdx.x;
    const int h = blockIdx.y * 4 + threadIdx.y;
    const int plane = blockIdx.z;

    const float* __restrict__ xp = x + (size_t)plane * KH * KW;

    const float c = xp[h * KW + w];

    float num = 0.0f;
    float den = 0.0f;

#pragma unroll
    for (int ki = 0; ki < 5; ++ki) {
        int hh = h + ki - 2;
        hh = (hh < 0) ? -hh : hh;
        hh = (hh >= KH) ? (2 * KH - 2 - hh) : hh;
        const float* __restrict__ row = xp + hh * KW;
#pragma unroll
        for (int kj = 0; kj < 5; ++kj) {
            int ww = w + kj - 2;
            ww = (ww < 0) ? -ww : ww;
            ww = (ww >= KW) ? (2 * KW - 2 - ww) : ww;
            const float p = row[ww];
            const float d = p - c;
            // weight_density normalization cancels in num/den -> skip it
            const float wt = __expf(-0.5f * d * d) * wsp[ki * 5 + kj];
            num = fmaf(wt, p, num);
            den += wt;
        }
    }

    out[(size_t)plane * KH * KW + h * KW + w] = num / den;
}

extern "C" void kernel_launch(void* const* d_in, const int* in_sizes, int n_in,
                              void* d_out, int out_size, void* d_ws, size_t ws_size,
                              hipStream_t stream) {
    const float* x   = (const float*)d_in[0];
    const float* wsp = (const float*)d_in[1];
    float* out = (float*)d_out;

    const int planes = out_size / (KH * KW);  // B*C = 12

    dim3 block(64, 4, 1);
    dim3 grid(KW / 64, KH / 4, planes);
    TrainableFilter_75118978007282_kernel<<<grid, block, 0, stream>>>(x, wsp, out);
}

// Round 4
// 24.488 us; speedup vs baseline: 1.1276x; 1.1276x over previous
//
#include <hip/hip_runtime.h>

#define KH 512
#define KW 512
#define TILE_H 4

__global__ __launch_bounds__(256)
void TrainableFilter_75118978007282_kernel(const float* __restrict__ x,
                                           const float* __restrict__ wsp,
                                           float* __restrict__ out) {
    // grid: (W/64, H/(4*TILE_H), B*C), block (64,4); each thread does TILE_H rows
    const int w  = blockIdx.x * 64 + threadIdx.x;
    const int h0 = (blockIdx.y * 4 + threadIdx.y) * TILE_H;
    const int plane = blockIdx.z;

    const float* __restrict__ xp = x + (size_t)plane * KH * KW;

    // reflect-resolved column indices (shared across all taps of this thread)
    int ww[5];
#pragma unroll
    for (int j = 0; j < 5; ++j) {
        int t = w + j - 2;
        t = (t < 0) ? -t : t;
        t = (t >= KW) ? (2 * KW - 2 - t) : t;
        ww[j] = t;
    }

    // register-resident 8x5 input window covering TILE_H output rows
    float pix[TILE_H + 4][5];
#pragma unroll
    for (int i = 0; i < TILE_H + 4; ++i) {
        int t = h0 + i - 2;
        t = (t < 0) ? -t : t;
        t = (t >= KH) ? (2 * KH - 2 - t) : t;
        const float* __restrict__ row = xp + t * KW;
#pragma unroll
        for (int j = 0; j < 5; ++j) pix[i][j] = row[ww[j]];
    }

    // spatial weights: uniform address -> scalar (SGPR) loads
    float wk[25];
#pragma unroll
    for (int k = 0; k < 25; ++k) wk[k] = wsp[k];

    // exp(-0.5*d^2) == exp2(-(d*s)^2), s = sqrt(0.5*log2(e));
    // v_exp_f32 computes 2^x natively
    const float S = 0.84932184f;

    float res[TILE_H];
#pragma unroll
    for (int r = 0; r < TILE_H; ++r) {
        const float c = pix[r + 2][2];
        float num = 0.0f, den = 0.0f;
#pragma unroll
        for (int i = 0; i < 5; ++i) {
#pragma unroll
            for (int j = 0; j < 5; ++j) {
                const float p  = pix[r + i][j];
                const float dm = (p - c) * S;
                const float g  = __builtin_amdgcn_exp2f(-dm * dm) * wk[i * 5 + j];
                num = fmaf(g, p, num);
                den += g;
            }
        }
        res[r] = __fdividef(num, den);
    }

#pragma unroll
    for (int r = 0; r < TILE_H; ++r)
        out[(size_t)plane * KH * KW + (size_t)(h0 + r) * KW + w] = res[r];
}

extern "C" void kernel_launch(void* const* d_in, const int* in_sizes, int n_in,
                              void* d_out, int out_size, void* d_ws, size_t ws_size,
                              hipStream_t stream) {
    const float* x   = (const float*)d_in[0];
    const float* wsp = (const float*)d_in[1];
    float* out = (float*)d_out;

    const int planes = out_size / (KH * KW);  // B*C = 12

    dim3 block(64, 4, 1);
    dim3 grid(KW / 64, KH / (4 * TILE_H), planes);
    TrainableFilter_75118978007282_kernel<<<grid, block, 0, stream>>>(x, wsp, out);
}

// Round 5
// 23.863 us; speedup vs baseline: 1.1572x; 1.0262x over previous
//
#include <hip/hip_runtime.h>

#define KH 512
#define KW 512
#define TW 4
#define TH 2

__global__ __launch_bounds__(256)
void TrainableFilter_75118978007282_kernel(const float* __restrict__ x,
                                           const float* __restrict__ wsp,
                                           float* __restrict__ out) {
    // block (64,4); each thread computes a TW x TH output tile
    const int tx = threadIdx.x;
    const int w0 = blockIdx.x * (64 * TW) + tx * TW;
    const int h0 = (blockIdx.y * 4 + threadIdx.y) * TH;
    const int plane = blockIdx.z;
    const float* __restrict__ xp = x + (size_t)plane * KH * KW;

    // edge lanes: clamp segment bases; reflected values are recovered from
    // registers already loaded (cndmask), never from extra loads
    const bool left  = (w0 == 0);
    const bool right = (w0 == KW - TW);
    const int b0 = left ? 0 : (w0 - 4);
    const int b2 = right ? (KW - 4) : (w0 + 4);

    // spatial weights: uniform -> scalar (SGPR) loads
    float wk[25];
#pragma unroll
    for (int k = 0; k < 25; ++k) wk[k] = wsp[k];

    // center pixels for the TH output rows (aligned float4, always in-bounds)
    float c[TH][TW];
#pragma unroll
    for (int r = 0; r < TH; ++r) {
        const float4 cv = *reinterpret_cast<const float4*>(xp + (size_t)(h0 + r) * KW + w0);
        c[r][0] = cv.x; c[r][1] = cv.y; c[r][2] = cv.z; c[r][3] = cv.w;
    }

    float num[TH][TW], den[TH][TW];
#pragma unroll
    for (int r = 0; r < TH; ++r)
#pragma unroll
        for (int q = 0; q < TW; ++q) { num[r][q] = 0.0f; den[r][q] = 0.0f; }

    const float NC2 = -0.72134752f;  // -0.5*log2(e): exp(-0.5 d^2) = exp2(d^2 * NC2)

    // stream TH+4 input rows; win[] stays register-resident (static indices only)
#pragma unroll
    for (int i = 0; i < TH + 4; ++i) {
        int hh = h0 + i - 2;
        hh = (hh < 0) ? -hh : hh;
        hh = (hh >= KH) ? (2 * KH - 2 - hh) : hh;
        const float* __restrict__ rp = xp + (size_t)hh * KW;

        const float4 s0 = *reinterpret_cast<const float4*>(rp + b0);
        const float4 s1 = *reinterpret_cast<const float4*>(rp + w0);
        const float4 s2 = *reinterpret_cast<const float4*>(rp + b2);
        float win[12] = { s0.x, s0.y, s0.z, s0.w,
                          s1.x, s1.y, s1.z, s1.w,
                          s2.x, s2.y, s2.z, s2.w };
        // reflect fixups:
        //  left  (w0==0, b0 clamped to 0): win[2] wants col -2 -> 2, slot already holds col 2;
        //        win[3] wants col -1 -> 1 = win[1]
        //  right (w0==508, b2 clamped to 508): win[8] wants col 512 -> 510 = win[6];
        //        win[9] wants col 513 -> 509 = win[5]
        win[3] = left ? win[1] : win[3];
        const float f8 = right ? win[6] : win[8];
        const float f9 = right ? win[5] : win[9];
        win[8] = f8; win[9] = f9;

#pragma unroll
        for (int r = 0; r < TH; ++r) {
            if (r <= i && i <= r + 4) {       // compile-time: row i is tap row ki for out row r
                const int ki = i - r;
#pragma unroll
                for (int q = 0; q < TW; ++q) {
                    const float cc = c[r][q];
#pragma unroll
                    for (int j = 0; j < 5; ++j) {
                        const float p = win[2 + q + j];
                        const float d = p - cc;
                        const float a = (d * d) * NC2;
                        const float e = __builtin_amdgcn_exp2f(a);
                        const float g = e * wk[ki * 5 + j];
                        num[r][q] = fmaf(g, p, num[r][q]);
                        den[r][q] += g;
                    }
                }
            }
        }
    }

#pragma unroll
    for (int r = 0; r < TH; ++r) {
        float4 o;
        o.x = __fdividef(num[r][0], den[r][0]);
        o.y = __fdividef(num[r][1], den[r][1]);
        o.z = __fdividef(num[r][2], den[r][2]);
        o.w = __fdividef(num[r][3], den[r][3]);
        *reinterpret_cast<float4*>(out + (size_t)plane * KH * KW + (size_t)(h0 + r) * KW + w0) = o;
    }
}

extern "C" void kernel_launch(void* const* d_in, const int* in_sizes, int n_in,
                              void* d_out, int out_size, void* d_ws, size_t ws_size,
                              hipStream_t stream) {
    const float* x   = (const float*)d_in[0];
    const float* wsp = (const float*)d_in[1];
    float* out = (float*)d_out;

    const int planes = out_size / (KH * KW);  // B*C = 12

    dim3 block(64, 4, 1);
    dim3 grid(KW / (64 * TW), KH / (4 * TH), planes);
    TrainableFilter_75118978007282_kernel<<<grid, block, 0, stream>>>(x, wsp, out);
}